// Round 2
// baseline (689.513 us; speedup 1.0000x reference)
//
#include <hip/hip_runtime.h>

typedef unsigned short u16;
typedef __bf16 bf16x8 __attribute__((ext_vector_type(8)));
typedef float f32x4 __attribute__((ext_vector_type(4)));
typedef u16 u16x4 __attribute__((ext_vector_type(4)));

#define AS1P(p) ((__attribute__((address_space(1))) void*)(unsigned long long)(p))
#define AS3P(p) ((__attribute__((address_space(3))) void*)(unsigned long long)(p))
#define MFMA16(a, b, c) __builtin_amdgcn_mfma_f32_16x16x32_bf16((a), (b), (c), 0, 0, 0)

__device__ __forceinline__ u16 f2b(float x) { return __builtin_bit_cast(u16, (__bf16)x); }

// ---------------- elementwise f32 -> bf16 ----------------
__global__ __launch_bounds__(256) void cvt_f32_bf16(const float* __restrict__ in,
                                                    u16* __restrict__ out, int n4) {
  int stride = gridDim.x * blockDim.x;
  for (int i = blockIdx.x * blockDim.x + threadIdx.x; i < n4; i += stride) {
    f32x4 v = *(const f32x4*)(in + (long)i * 4);
    u16x4 o;
    o[0] = f2b(v[0]); o[1] = f2b(v[1]); o[2] = f2b(v[2]); o[3] = f2b(v[3]);
    *(u16x4*)(out + (long)i * 4) = o;
  }
}

// ---------------- weight transpose f32[K][N] -> bf16[N][K] ----------------
__global__ __launch_bounds__(256) void wtrans(const float* __restrict__ W,
                                              u16* __restrict__ Wt, int K, int N) {
  __shared__ float tile[32][33];
  int nbk = K >> 5;
  int bk = blockIdx.x % nbk;
  int bn = blockIdx.x / nbk;
  int tx = threadIdx.x & 31, ty = threadIdx.x >> 5;  // 32 x 8
#pragma unroll
  for (int i = 0; i < 32; i += 8)
    tile[ty + i][tx] = W[(long)(bk * 32 + ty + i) * N + bn * 32 + tx];
  __syncthreads();
#pragma unroll
  for (int i = 0; i < 32; i += 8)
    Wt[(long)(bn * 32 + ty + i) * K + bk * 32 + tx] = f2b(tile[tx][ty + i]);
}

// ---------------- v transpose bf16 [8][256][1024] -> [8][1024][256] ----------------
__global__ __launch_bounds__(256) void vtrans(const u16* __restrict__ v, u16* __restrict__ vt) {
  __shared__ u16 tile[32][33];
  int bt = blockIdx.x & 7;          // Se/32
  int bd = (blockIdx.x >> 3) & 31;  // D/32
  int bc = blockIdx.x >> 8;         // 8
  int tx = threadIdx.x & 31, ty = threadIdx.x >> 5;
  const long vb = (long)bc * 256 * 1024;
  const long ob = (long)bc * 1024 * 256;
#pragma unroll
  for (int i = 0; i < 32; i += 8)
    tile[ty + i][tx] = v[vb + (long)(bt * 32 + ty + i) * 1024 + bd * 32 + tx];
  __syncthreads();
#pragma unroll
  for (int i = 0; i < 32; i += 8)
    vt[ob + (long)(bd * 32 + ty + i) * 256 + bt * 32 + tx] = tile[tx][ty + i];
}

// ---------------- GEMM: C[M,N] = A[M,K] @ Bt[N,K]^T (bf16 in, MFMA 16x16x32) ----------
// MODE 0: write bf16 C.   MODE 1: write f32 C + bias[n] + resid[m*N+n] (final output).
template <int MODE>
__global__ __launch_bounds__(256) void gemm_bt(
    const u16* __restrict__ A, const u16* __restrict__ Bt,
    u16* __restrict__ outb, float* __restrict__ outf,
    const float* __restrict__ bias, const float* __restrict__ resid,
    int M, int N, int K) {
  __shared__ u16 lA[128 * 64];  // [row][k], 16B-slot XOR swizzled by (row&7)
  __shared__ u16 lB[128 * 64];
  const int tid = threadIdx.x;
  const int lane = tid & 63;
  const int wid = tid >> 6;
  const int wm = wid >> 1, wn = wid & 1;
  const int lr = lane & 15, lg = lane >> 4;

  const int nbn = N >> 7;
  const int bm = (int)blockIdx.x / nbn;
  const int bn = (int)blockIdx.x % nbn;
  const long arow0 = (long)bm * 128;
  const long brow0 = (long)bn * 128;

  f32x4 acc[4][4] = {};

  const int srow = tid >> 3;   // staging row within 32-row group
  const int scol = tid & 7;    // staging 16B slot

  for (int k0 = 0; k0 < K; k0 += 64) {
#pragma unroll
    for (int i = 0; i < 4; ++i) {
      int row = i * 32 + srow;
      int kc = scol ^ (row & 7);  // pre-swizzled global source
      __builtin_amdgcn_global_load_lds(AS1P(A + (arow0 + row) * K + k0 + kc * 8),
                                       AS3P(lA + i * 2048 + (tid & ~63) * 8), 16, 0, 0);
    }
#pragma unroll
    for (int i = 0; i < 4; ++i) {
      int row = i * 32 + srow;
      int kc = scol ^ (row & 7);
      __builtin_amdgcn_global_load_lds(AS1P(Bt + (brow0 + row) * K + k0 + kc * 8),
                                       AS3P(lB + i * 2048 + (tid & ~63) * 8), 16, 0, 0);
    }
    asm volatile("s_waitcnt vmcnt(0)" ::: "memory");
    __syncthreads();

#pragma unroll
    for (int ks = 0; ks < 2; ++ks) {
      bf16x8 af[4], bfr[4];
#pragma unroll
      for (int m = 0; m < 4; ++m) {
        int row = wm * 64 + m * 16 + lr;
        int off = row * 128 + ks * 64 + lg * 16;
        off ^= (row & 7) << 4;
        af[m] = *(const bf16x8*)((const char*)lA + off);
      }
#pragma unroll
      for (int n = 0; n < 4; ++n) {
        int row = wn * 64 + n * 16 + lr;
        int off = row * 128 + ks * 64 + lg * 16;
        off ^= (row & 7) << 4;
        bfr[n] = *(const bf16x8*)((const char*)lB + off);
      }
#pragma unroll
      for (int m = 0; m < 4; ++m)
#pragma unroll
        for (int n = 0; n < 4; ++n)
          acc[m][n] = MFMA16(af[m], bfr[n], acc[m][n]);
    }
    __syncthreads();
  }

  // epilogue: C/D layout row=(lane>>4)*4+r, col=lane&15
#pragma unroll
  for (int m = 0; m < 4; ++m) {
#pragma unroll
    for (int n = 0; n < 4; ++n) {
      long col = brow0 + wn * 64 + n * 16 + lr;
#pragma unroll
      for (int r = 0; r < 4; ++r) {
        long row = arow0 + wm * 64 + m * 16 + lg * 4 + r;
        float v = acc[m][n][r];
        if (MODE == 0) {
          outb[row * N + col] = f2b(v);
        } else {
          long idx = row * N + col;
          outf[idx] = v + bias[col] + resid[idx];
        }
      }
    }
  }
}

// ---------------- fused decomposing attention (v2: no K/V staging, no barriers) -------
// grid: b(2) x h(16) x sblk(64); block 256 = 4 waves x 16 s-rows.
// Component softmax is pointwise in t -> no cross-t reduction; all 4 components'
// scores held in-lane. K/V fragments read straight from global (L2-resident:
// 256 KB per (b,h), shared by 64 blocks). LDS only for wave-private P slab.
__global__ __launch_bounds__(256) void attn_fused(
    const u16* __restrict__ q,   // [BC][S][D] bf16
    const u16* __restrict__ k,   // [BC][Se][D] bf16
    const u16* __restrict__ vt,  // [BC][D][Se] bf16
    u16* __restrict__ attn,      // [BC][S][D] bf16
    float* __restrict__ ent) {   // [B][H][S][Se] f32
  const int B = 2, H = 16, S = 4096, Se = 256, D = 1024;
  // per-wave P slab: [c:4][s:16][t-pitch:72] u16 = 4608 u16 = 9216 B (pitch 144 B
  // rotates banks by 4/row -> worst 2-way alias on both write & read = free)
  __shared__ u16 ldsP[4 * 4608];
  const int tid = threadIdx.x;
  const int lane = tid & 63, wid = tid >> 6;
  const int lr = lane & 15, lg = lane >> 4;
  const int sblk = blockIdx.x & 63;
  const int h = (blockIdx.x >> 6) & 15;
  const int b = blockIdx.x >> 10;
  const int s0 = sblk * 64 + wid * 16;

  u16* P = ldsP + wid * 4608;

  // hoist Q fragments (A-frag: row=lr, k=ks*32+lg*8+e)
  bf16x8 qf[4][2];
#pragma unroll
  for (int c = 0; c < 4; ++c)
#pragma unroll
    for (int ks = 0; ks < 2; ++ks)
      qf[c][ks] = *(const bf16x8*)(q + ((c * B + b) * (long)S + s0 + lr) * D +
                                   h * 64 + ks * 32 + lg * 8);

  f32x4 oacc[4][4] = {};  // [c][dh-subtile]

  for (int tc = 0; tc < 4; ++tc) {
    // ---- QK^T + softmax in two 32-t half chunks (halves sacc live registers)
#pragma unroll
    for (int th = 0; th < 2; ++th) {
      f32x4 sacc[4][2] = {};  // [c][t-subtile within half]
#pragma unroll
      for (int c = 0; c < 4; ++c) {
#pragma unroll
        for (int tsl = 0; tsl < 2; ++tsl) {
          int trow = tc * 64 + (th * 2 + tsl) * 16 + lr;
#pragma unroll
          for (int ks = 0; ks < 2; ++ks) {
            bf16x8 kf = *(const bf16x8*)(k + ((c * B + b) * (long)Se + trow) * D +
                                         h * 64 + ks * 32 + lg * 8);
            sacc[c][tsl] = MFMA16(qf[c][ks], kf, sacc[c][tsl]);
          }
        }
      }
      // in-lane component softmax + entropy + P write
#pragma unroll
      for (int tsl = 0; tsl < 2; ++tsl) {
#pragma unroll
        for (int r = 0; r < 4; ++r) {
          float v0 = sacc[0][tsl][r] * 0.125f;
          float v1 = sacc[1][tsl][r] * 0.125f;
          float v2 = sacc[2][tsl][r] * 0.125f;
          float v3 = sacc[3][tsl][r] * 0.125f;
          float mx = fmaxf(fmaxf(v0, v1), fmaxf(v2, v3));
          float e0 = __expf(v0 - mx), e1 = __expf(v1 - mx);
          float e2 = __expf(v2 - mx), e3 = __expf(v3 - mx);
          float sum = e0 + e1 + e2 + e3;
          float inv = 1.0f / sum;
          float lse = __logf(sum);
          float w0 = e0 * inv, w1 = e1 * inv, w2 = e2 * inv, w3 = e3 * inv;
          float entv = w0 * (v0 - mx - lse) + w1 * (v1 - mx - lse) +
                       w2 * (v2 - mx - lse) + w3 * (v3 - mx - lse);
          int tl = (th * 2 + tsl) * 16 + lr;  // t within 64-chunk
          int s = s0 + lg * 4 + r;
          ent[((b * H + h) * (long)S + s) * Se + tc * 64 + tl] = entv;
          int prow = lg * 4 + r;
          const float rs = 1.0f / 64.0f;  // C/Se
          P[0 * 1152 + prow * 72 + tl] = f2b(w0 * rs);
          P[1 * 1152 + prow * 72 + tl] = f2b(w1 * rs);
          P[2 * 1152 + prow * 72 + tl] = f2b(w2 * rs);
          P[3 * 1152 + prow * 72 + tl] = f2b(w3 * rs);
        }
      }
    }

    // ---- PV (wave-private LDS: no barrier; compiler inserts lgkmcnt waits)
#pragma unroll
    for (int c = 0; c < 4; ++c) {
      bf16x8 pf[2];
#pragma unroll
      for (int ks = 0; ks < 2; ++ks)
        pf[ks] = *(const bf16x8*)(P + c * 1152 + lr * 72 + ks * 32 + lg * 8);
#pragma unroll
      for (int dsu = 0; dsu < 4; ++dsu) {
#pragma unroll
        for (int ks = 0; ks < 2; ++ks) {
          bf16x8 vf = *(const bf16x8*)(vt + ((c * B + b) * (long)D + h * 64 +
                                             dsu * 16 + lr) * Se +
                                       tc * 64 + ks * 32 + lg * 8);
          oacc[c][dsu] = MFMA16(pf[ks], vf, oacc[c][dsu]);
        }
      }
    }
  }

  // ---- epilogue: write attn out bf16
#pragma unroll
  for (int c = 0; c < 4; ++c)
#pragma unroll
    for (int dsu = 0; dsu < 4; ++dsu)
#pragma unroll
      for (int r = 0; r < 4; ++r) {
        int s = s0 + lg * 4 + r;
        attn[((c * B + b) * (long)S + s) * D + h * 64 + dsu * 16 + lr] =
            f2b(oacc[c][dsu][r]);
      }
}

extern "C" void kernel_launch(void* const* d_in, const int* in_sizes, int n_in,
                              void* d_out, int out_size, void* d_ws, size_t ws_size,
                              hipStream_t stream) {
  const float* hs  = (const float*)d_in[0];  // [8,4096,1024]
  const float* ehs = (const float*)d_in[1];  // [8,256,2048]
  const float* Wq  = (const float*)d_in[2];  // [1024,1024]
  const float* Wk  = (const float*)d_in[3];  // [2048,1024]
  const float* Wv  = (const float*)d_in[4];  // [2048,1024]
  const float* Wo  = (const float*)d_in[5];  // [1024,1024]
  const float* bo  = (const float*)d_in[6];  // [1024]
  float* out = (float*)d_out;
  float* ent = out + (size_t)8 * 4096 * 1024;

  char* ws = (char*)d_ws;
  u16* hsb  = (u16*)(ws);              // 67,108,864 B (bf16 hs; later reused as attn out)
  u16* ehsb = (u16*)(ws + 67108864);   //  8,388,608 B
  u16* wqT  = (u16*)(ws + 75497472);   //  2,097,152 B
  u16* wkT  = (u16*)(ws + 77594624);   //  4,194,304 B
  u16* wvT  = (u16*)(ws + 81788928);   //  4,194,304 B
  u16* woT  = (u16*)(ws + 85983232);   //  2,097,152 B
  u16* qb   = (u16*)(ws + 88080384);   // 67,108,864 B
  u16* kb   = (u16*)(ws + 155189248);  //  4,194,304 B
  u16* vtmp = (u16*)(ws + 159383552);  //  4,194,304 B
  u16* vtb  = (u16*)(ws + 163577856);  //  4,194,304 B  (end: 167,772,160)

  cvt_f32_bf16<<<2048, 256, 0, stream>>>(hs, hsb, (8 * 4096 * 1024) / 4);
  cvt_f32_bf16<<<512, 256, 0, stream>>>(ehs, ehsb, (8 * 256 * 2048) / 4);
  wtrans<<<1024, 256, 0, stream>>>(Wq, wqT, 1024, 1024);
  wtrans<<<2048, 256, 0, stream>>>(Wk, wkT, 2048, 1024);
  wtrans<<<2048, 256, 0, stream>>>(Wv, wvT, 2048, 1024);
  wtrans<<<1024, 256, 0, stream>>>(Wo, woT, 1024, 1024);
  // q = hs @ Wq
  gemm_bt<0><<<(32768 / 128) * (1024 / 128), 256, 0, stream>>>(
      hsb, wqT, qb, nullptr, nullptr, nullptr, 32768, 1024, 1024);
  // k = ehs @ Wk
  gemm_bt<0><<<(2048 / 128) * (1024 / 128), 256, 0, stream>>>(
      ehsb, wkT, kb, nullptr, nullptr, nullptr, 2048, 1024, 2048);
  // v = ehs @ Wv
  gemm_bt<0><<<(2048 / 128) * (1024 / 128), 256, 0, stream>>>(
      ehsb, wvT, vtmp, nullptr, nullptr, nullptr, 2048, 1024, 2048);
  vtrans<<<2048, 256, 0, stream>>>(vtmp, vtb);
  // fused component-softmax attention (writes attn into hsb region + entropy to d_out)
  attn_fused<<<2048, 256, 0, stream>>>(qb, kb, vtb, hsb, ent);
  // out = attn @ Wo + bo + hs
  gemm_bt<1><<<(32768 / 128) * (1024 / 128), 256, 0, stream>>>(
      hsb, woT, nullptr, out, bo, hs, 32768, 1024, 1024);
}

// Round 3
// 572.266 us; speedup vs baseline: 1.2049x; 1.2049x over previous
//
#include <hip/hip_runtime.h>

typedef unsigned short u16;
typedef __bf16 bf16x4 __attribute__((ext_vector_type(4)));
typedef __bf16 bf16x8 __attribute__((ext_vector_type(8)));
typedef float f32x4 __attribute__((ext_vector_type(4)));
typedef u16 u16x4 __attribute__((ext_vector_type(4)));

#define AS1P(p) ((__attribute__((address_space(1))) void*)(unsigned long long)(p))
#define AS3P(p) ((__attribute__((address_space(3))) void*)(unsigned long long)(p))
#define MFMA16(a, b, c) __builtin_amdgcn_mfma_f32_16x16x32_bf16((a), (b), (c), 0, 0, 0)

__device__ __forceinline__ u16 f2b(float x) { return __builtin_bit_cast(u16, (__bf16)x); }

// ---------------- elementwise f32 -> bf16 ----------------
__global__ __launch_bounds__(256) void cvt_f32_bf16(const float* __restrict__ in,
                                                    u16* __restrict__ out, int n4) {
  int stride = gridDim.x * blockDim.x;
  for (int i = blockIdx.x * blockDim.x + threadIdx.x; i < n4; i += stride) {
    f32x4 v = *(const f32x4*)(in + (long)i * 4);
    u16x4 o;
    o[0] = f2b(v[0]); o[1] = f2b(v[1]); o[2] = f2b(v[2]); o[3] = f2b(v[3]);
    *(u16x4*)(out + (long)i * 4) = o;
  }
}

// ---------------- weight transpose f32[K][N] -> bf16[N][K] ----------------
__global__ __launch_bounds__(256) void wtrans(const float* __restrict__ W,
                                              u16* __restrict__ Wt, int K, int N) {
  __shared__ float tile[32][33];
  int nbk = K >> 5;
  int bk = blockIdx.x % nbk;
  int bn = blockIdx.x / nbk;
  int tx = threadIdx.x & 31, ty = threadIdx.x >> 5;  // 32 x 8
#pragma unroll
  for (int i = 0; i < 32; i += 8)
    tile[ty + i][tx] = W[(long)(bk * 32 + ty + i) * N + bn * 32 + tx];
  __syncthreads();
#pragma unroll
  for (int i = 0; i < 32; i += 8)
    Wt[(long)(bn * 32 + ty + i) * K + bk * 32 + tx] = f2b(tile[tx][ty + i]);
}

// ---------------- v transpose bf16 [8][256][1024] -> [8][1024][256] ----------------
__global__ __launch_bounds__(256) void vtrans(const u16* __restrict__ v, u16* __restrict__ vt) {
  __shared__ u16 tile[32][33];
  int bt = blockIdx.x & 7;          // Se/32
  int bd = (blockIdx.x >> 3) & 31;  // D/32
  int bc = blockIdx.x >> 8;         // 8
  int tx = threadIdx.x & 31, ty = threadIdx.x >> 5;
  const long vb = (long)bc * 256 * 1024;
  const long ob = (long)bc * 1024 * 256;
#pragma unroll
  for (int i = 0; i < 32; i += 8)
    tile[ty + i][tx] = v[vb + (long)(bt * 32 + ty + i) * 1024 + bd * 32 + tx];
  __syncthreads();
#pragma unroll
  for (int i = 0; i < 32; i += 8)
    vt[ob + (long)(bd * 32 + ty + i) * 256 + bt * 32 + tx] = tile[tx][ty + i];
}

// ---------------- GEMM: C[M,N] = A[M,K] @ Bt[N,K]^T (bf16 in, MFMA 16x16x32) ----------
// MODE 0: write bf16 C.   MODE 1: write f32 C + bias[n] + resid[m*N+n] (final output).
template <int MODE>
__global__ __launch_bounds__(256) void gemm_bt(
    const u16* __restrict__ A, const u16* __restrict__ Bt,
    u16* __restrict__ outb, float* __restrict__ outf,
    const float* __restrict__ bias, const float* __restrict__ resid,
    int M, int N, int K) {
  __shared__ u16 lA[128 * 64];  // [row][k], 16B-slot XOR swizzled by (row&7)
  __shared__ u16 lB[128 * 64];
  const int tid = threadIdx.x;
  const int lane = tid & 63;
  const int wid = tid >> 6;
  const int wm = wid >> 1, wn = wid & 1;
  const int lr = lane & 15, lg = lane >> 4;

  // XCD-aware bijective swizzle (nwg % 8 == 0 for all our launches)
  int bid = (int)blockIdx.x;
  int nwg = (int)gridDim.x;
  if ((nwg & 7) == 0) bid = (bid & 7) * (nwg >> 3) + (bid >> 3);

  const int nbn = N >> 7;
  const int bm = bid / nbn;
  const int bn = bid % nbn;
  const long arow0 = (long)bm * 128;
  const long brow0 = (long)bn * 128;

  f32x4 acc[4][4] = {};

  const int srow = tid >> 3;   // staging row within 32-row group
  const int scol = tid & 7;    // staging 16B slot

  for (int k0 = 0; k0 < K; k0 += 64) {
#pragma unroll
    for (int i = 0; i < 4; ++i) {
      int row = i * 32 + srow;
      int kc = scol ^ (row & 7);  // pre-swizzled global source
      __builtin_amdgcn_global_load_lds(AS1P(A + (arow0 + row) * K + k0 + kc * 8),
                                       AS3P(lA + i * 2048 + (tid & ~63) * 8), 16, 0, 0);
    }
#pragma unroll
    for (int i = 0; i < 4; ++i) {
      int row = i * 32 + srow;
      int kc = scol ^ (row & 7);
      __builtin_amdgcn_global_load_lds(AS1P(Bt + (brow0 + row) * K + k0 + kc * 8),
                                       AS3P(lB + i * 2048 + (tid & ~63) * 8), 16, 0, 0);
    }
    asm volatile("s_waitcnt vmcnt(0)" ::: "memory");
    __syncthreads();

#pragma unroll
    for (int ks = 0; ks < 2; ++ks) {
      bf16x8 af[4], bfr[4];
#pragma unroll
      for (int m = 0; m < 4; ++m) {
        int row = wm * 64 + m * 16 + lr;
        int off = row * 128 + ks * 64 + lg * 16;
        off ^= (row & 7) << 4;
        af[m] = *(const bf16x8*)((const char*)lA + off);
      }
#pragma unroll
      for (int n = 0; n < 4; ++n) {
        int row = wn * 64 + n * 16 + lr;
        int off = row * 128 + ks * 64 + lg * 16;
        off ^= (row & 7) << 4;
        bfr[n] = *(const bf16x8*)((const char*)lB + off);
      }
#pragma unroll
      for (int m = 0; m < 4; ++m)
#pragma unroll
        for (int n = 0; n < 4; ++n)
          acc[m][n] = MFMA16(af[m], bfr[n], acc[m][n]);
    }
    __syncthreads();
  }

  // epilogue: C/D layout row=(lane>>4)*4+r, col=lane&15
#pragma unroll
  for (int m = 0; m < 4; ++m) {
#pragma unroll
    for (int n = 0; n < 4; ++n) {
      long col = brow0 + wn * 64 + n * 16 + lr;
#pragma unroll
      for (int r = 0; r < 4; ++r) {
        long row = arow0 + wm * 64 + m * 16 + lg * 4 + r;
        float v = acc[m][n][r];
        if (MODE == 0) {
          outb[row * N + col] = f2b(v);
        } else {
          long idx = row * N + col;
          outf[idx] = v + bias[col] + resid[idx];
        }
      }
    }
  }
}

// ---------------- fused decomposing attention (v3) ----------------
// grid: 2048 blocks (b2 x h16 x sblk64), block 256 = 4 waves x 16 s-rows.
// K staged coalesced in 32-t chunks, double-buffered, 1 barrier/chunk.
// V read scattered from global (L2-resident, deep ILP under MFMA).
// P slab wave-private (pitch 36 u16 -> conflict-free), no P barriers.
__global__ __launch_bounds__(256) void attn_fused(
    const u16* __restrict__ q,   // [BC][S][D] bf16
    const u16* __restrict__ k,   // [BC][Se][D] bf16
    const u16* __restrict__ vt,  // [BC][D][Se] bf16
    u16* __restrict__ attn,      // [BC][S][D] bf16
    float* __restrict__ ent) {   // [B][H][S][Se] f32
  const int B = 2, H = 16, S = 4096, Se = 256, D = 1024;
  __shared__ u16 ldsK[2][8192];   // 2 x 16KB: [c:4][t:32][dh-slot:8 x 8], row-XOR slots
  __shared__ u16 ldsP[4 * 2304];  // per wave: [c:4][s:16][pitch 36]
  const int tid = threadIdx.x;
  const int lane = tid & 63, wid = tid >> 6;
  const int lr = lane & 15, lg = lane >> 4;
  int bid = (int)blockIdx.x;
  bid = (bid & 7) * 256 + (bid >> 3);  // XCD swizzle (2048 blocks)
  const int sblk = bid & 63;
  const int h = (bid >> 6) & 15;
  const int b = bid >> 10;
  const int s0 = sblk * 64 + wid * 16;

  // --- K staging decode: instr index = component c; this wave covers t-rows wid*8..+8
  const int strow = wid * 8 + (lane >> 3);      // t-row within 32-chunk
  const int sslot = (lane & 7) ^ (strow & 7);   // pre-swizzled global 16B slot
  const u16* kbase = k + ((long)b * Se + strow) * D + h * 64 + sslot * 8;
  const long KCSTR = (long)B * Se * D;          // component stride in k

  u16* Pw = ldsP + wid * 2304;

  // --- hoisted Q fragments: A-frag row=lr, k=ks*32+lg*8+e
  bf16x8 qf[4][2];
#pragma unroll
  for (int c = 0; c < 4; ++c)
#pragma unroll
    for (int ks = 0; ks < 2; ++ks)
      qf[c][ks] = *(const bf16x8*)(q + ((c * B + b) * (long)S + s0 + lr) * D +
                                   h * 64 + ks * 32 + lg * 8);

  float* entp = ent + ((long)(b * H + h) * S + s0 + lg * 4) * Se + lr;
  const u16* vbase = vt + ((long)b * D + h * 64 + lr) * Se + lg * 8;
  const long VCSTR = (long)B * D * Se;  // component stride in vt

  f32x4 oacc[4][4] = {};  // [c][dh-subtile]

  // prologue: stage chunk 0 into buf 0
#pragma unroll
  for (int c = 0; c < 4; ++c)
    __builtin_amdgcn_global_load_lds(AS1P(kbase + c * KCSTR),
                                     AS3P(&ldsK[0][c * 2048 + wid * 512]), 16, 0, 0);

  const float SC = 0.125f * 1.44269504f;   // scale * log2(e)
  const float LN2 = 0.69314718056f;
  const float RS = 1.0f / 64.0f;           // C/Se

#pragma unroll
  for (int ch = 0; ch < 8; ++ch) {
    const int cur = ch & 1;
    asm volatile("s_waitcnt vmcnt(0)" ::: "memory");
    __syncthreads();
    if (ch < 7) {
#pragma unroll
      for (int c = 0; c < 4; ++c)
        __builtin_amdgcn_global_load_lds(
            AS1P(kbase + (long)(ch + 1) * 32 * D + c * KCSTR),
            AS3P(&ldsK[cur ^ 1][c * 2048 + wid * 512]), 16, 0, 0);
    }
    const u16* KB = ldsK[cur];

    // ---- QK^T: B-frag(K): row t=tsl*16+lr, k=ks*32+lg*8 (swizzled slot)
    f32x4 sacc[4][2] = {};
#pragma unroll
    for (int c = 0; c < 4; ++c)
#pragma unroll
      for (int tsl = 0; tsl < 2; ++tsl) {
        int trow = tsl * 16 + lr;
#pragma unroll
        for (int ks = 0; ks < 2; ++ks) {
          int off = c * 2048 + trow * 64 + (((ks * 4 + lg) ^ (trow & 7)) * 8);
          bf16x8 kf = *(const bf16x8*)(KB + off);
          sacc[c][tsl] = MFMA16(qf[c][ks], kf, sacc[c][tsl]);
        }
      }

    // ---- in-lane component softmax + entropy + P write
#pragma unroll
    for (int tsl = 0; tsl < 2; ++tsl) {
#pragma unroll
      for (int r = 0; r < 4; ++r) {
        float t0 = sacc[0][tsl][r] * SC;
        float t1 = sacc[1][tsl][r] * SC;
        float t2 = sacc[2][tsl][r] * SC;
        float t3 = sacc[3][tsl][r] * SC;
        float mx = fmaxf(fmaxf(t0, t1), fmaxf(t2, t3));
        float e0 = __builtin_amdgcn_exp2f(t0 - mx);
        float e1 = __builtin_amdgcn_exp2f(t1 - mx);
        float e2 = __builtin_amdgcn_exp2f(t2 - mx);
        float e3 = __builtin_amdgcn_exp2f(t3 - mx);
        float sum = (e0 + e1) + (e2 + e3);
        float inv = __builtin_amdgcn_rcpf(sum);
        float l2s = __builtin_amdgcn_logf(sum);
        float w0 = e0 * inv, w1 = e1 * inv, w2 = e2 * inv, w3 = e3 * inv;
        // sum_c w_c * ln w_c = ln2 * (sum_c w_c*t_c - mx - log2(sum))
        float entv = (w0 * t0 + w1 * t1 + w2 * t2 + w3 * t3 - mx - l2s) * LN2;
        entp[r * Se + ch * 32 + tsl * 16] = entv;
        int pof = (lg * 4 + r) * 36 + tsl * 16 + lr;
        Pw[0 * 576 + pof] = f2b(w0 * RS);
        Pw[1 * 576 + pof] = f2b(w1 * RS);
        Pw[2 * 576 + pof] = f2b(w2 * RS);
        Pw[3 * 576 + pof] = f2b(w3 * RS);
      }
    }

    // ---- PV: A-frag(P): row s=lr, k=t=lg*8+e; B-frag(V^T): col dh=dsu*16+lr
#pragma unroll
    for (int c = 0; c < 4; ++c) {
      union { bf16x4 h[2]; bf16x8 v; } pu;
      pu.h[0] = *(const bf16x4*)(Pw + c * 576 + lr * 36 + lg * 8);
      pu.h[1] = *(const bf16x4*)(Pw + c * 576 + lr * 36 + lg * 8 + 4);
      bf16x8 pf = pu.v;
#pragma unroll
      for (int dsu = 0; dsu < 4; ++dsu) {
        bf16x8 vf = *(const bf16x8*)(vbase + c * VCSTR + dsu * 16 * Se + ch * 32);
        oacc[c][dsu] = MFMA16(pf, vf, oacc[c][dsu]);
      }
    }
  }

  // ---- epilogue: write attn out bf16
#pragma unroll
  for (int c = 0; c < 4; ++c)
#pragma unroll
    for (int dsu = 0; dsu < 4; ++dsu)
#pragma unroll
      for (int r = 0; r < 4; ++r) {
        int s = s0 + lg * 4 + r;
        attn[((c * B + b) * (long)S + s) * D + h * 64 + dsu * 16 + lr] =
            f2b(oacc[c][dsu][r]);
      }
}

extern "C" void kernel_launch(void* const* d_in, const int* in_sizes, int n_in,
                              void* d_out, int out_size, void* d_ws, size_t ws_size,
                              hipStream_t stream) {
  const float* hs  = (const float*)d_in[0];  // [8,4096,1024]
  const float* ehs = (const float*)d_in[1];  // [8,256,2048]
  const float* Wq  = (const float*)d_in[2];  // [1024,1024]
  const float* Wk  = (const float*)d_in[3];  // [2048,1024]
  const float* Wv  = (const float*)d_in[4];  // [2048,1024]
  const float* Wo  = (const float*)d_in[5];  // [1024,1024]
  const float* bo  = (const float*)d_in[6];  // [1024]
  float* out = (float*)d_out;
  float* ent = out + (size_t)8 * 4096 * 1024;

  char* ws = (char*)d_ws;
  u16* hsb  = (u16*)(ws);              // 67,108,864 B (bf16 hs; later reused as attn out)
  u16* ehsb = (u16*)(ws + 67108864);   //  8,388,608 B
  u16* wqT  = (u16*)(ws + 75497472);   //  2,097,152 B
  u16* wkT  = (u16*)(ws + 77594624);   //  4,194,304 B
  u16* wvT  = (u16*)(ws + 81788928);   //  4,194,304 B
  u16* woT  = (u16*)(ws + 85983232);   //  2,097,152 B
  u16* qb   = (u16*)(ws + 88080384);   // 67,108,864 B
  u16* kb   = (u16*)(ws + 155189248);  //  4,194,304 B
  u16* vtmp = (u16*)(ws + 159383552);  //  4,194,304 B
  u16* vtb  = (u16*)(ws + 163577856);  //  4,194,304 B  (end: 167,772,160)

  cvt_f32_bf16<<<2048, 256, 0, stream>>>(hs, hsb, (8 * 4096 * 1024) / 4);
  cvt_f32_bf16<<<512, 256, 0, stream>>>(ehs, ehsb, (8 * 256 * 2048) / 4);
  wtrans<<<1024, 256, 0, stream>>>(Wq, wqT, 1024, 1024);
  wtrans<<<2048, 256, 0, stream>>>(Wk, wkT, 2048, 1024);
  wtrans<<<2048, 256, 0, stream>>>(Wv, wvT, 2048, 1024);
  wtrans<<<1024, 256, 0, stream>>>(Wo, woT, 1024, 1024);
  // q = hs @ Wq
  gemm_bt<0><<<(32768 / 128) * (1024 / 128), 256, 0, stream>>>(
      hsb, wqT, qb, nullptr, nullptr, nullptr, 32768, 1024, 1024);
  // k = ehs @ Wk
  gemm_bt<0><<<(2048 / 128) * (1024 / 128), 256, 0, stream>>>(
      ehsb, wkT, kb, nullptr, nullptr, nullptr, 2048, 1024, 2048);
  // v = ehs @ Wv
  gemm_bt<0><<<(2048 / 128) * (1024 / 128), 256, 0, stream>>>(
      ehsb, wvT, vtmp, nullptr, nullptr, nullptr, 2048, 1024, 2048);
  vtrans<<<2048, 256, 0, stream>>>(vtmp, vtb);
  // fused component-softmax attention (writes attn into hsb region + entropy to d_out)
  attn_fused<<<2048, 256, 0, stream>>>(qb, kb, vtb, hsb, ent);
  // out = attn @ Wo + bo + hs
  gemm_bt<1><<<(32768 / 128) * (1024 / 128), 256, 0, stream>>>(
      hsb, woT, nullptr, out, bo, hs, 32768, 1024, 1024);
}